// Round 3
// baseline (113.828 us; speedup 1.0000x reference)
//
#include <hip/hip_runtime.h>

// SNN forward: T=128, B=8192, I=2, H=256, O=2
//  cur[t,b,h] = x[t,b,0]*W1[h,0] + x[t,b,1]*W1[h,1]
//  scan: reset = (mem>1); mem = 0.9*mem + cur - reset; spk = (mem>1)
//  out[b,o] = (mean of spk over last 10 t) dot W2[o,:]
//
// R3: x values are block-uniform -> read them via wave-uniform global loads so
// the compiler emits s_load_dwordx16 (scalar pipe / K$). This removes ALL LDS
// traffic and VGPR staging from the recurrence loop (R2 was part-bound on
// 4x ds_read_b128 per t across 16 waves/CU sharing one LDS unit).
// R=8 batch rows per thread keeps full 64B-line consumption (FETCH ~8.3 MB).
//
// Numerics: per-op fp32 rounding (__fmul_rn/__fadd_rn/__fsub_rn, no FMA),
// identical op order + identical reduction order/thread mapping to the
// R1/R2 kernels that measured absmax 0.0.

#define T_STEPS 128
#define BATCH   8192
#define IN_N    2
#define HID     256
#define OUT_N   2
#define TAIL    10
#define R       8

__global__ __launch_bounds__(256) void snn_fwd(const float* __restrict__ x,
                                               const float* __restrict__ W1,
                                               const float* __restrict__ W2,
                                               float* __restrict__ out) {
    const int h  = threadIdx.x;          // hidden unit 0..255
    const int b0 = blockIdx.x * R;       // first batch row of this block

    const float w0 = W1[2 * h];
    const float w1 = W1[2 * h + 1];

    // x slice for this block: 16 consecutive floats per t (64 B, line-aligned),
    // at wave-uniform addresses -> scalar loads.
    const float* xb = x + (size_t)blockIdx.x * (R * IN_N);

    float mem[R], spk[R], cnt[R];
#pragma unroll
    for (int r = 0; r < R; ++r) { mem[r] = 0.0f; spk[r] = 0.0f; cnt[r] = 0.0f; }

#define STEP(r, xa, xb_)                                                         \
    {                                                                            \
        const float c = __fadd_rn(__fmul_rn((xa), w0), __fmul_rn((xb_), w1));    \
        mem[r] = __fsub_rn(__fadd_rn(__fmul_rn(0.9f, mem[r]), c), spk[r]);       \
        spk[r] = (mem[r] > 1.0f) ? 1.0f : 0.0f;                                  \
    }

#pragma unroll 4
    for (int t = 0; t < T_STEPS - TAIL; ++t) {
        const float* xt = xb + (size_t)t * (BATCH * IN_N);
        float xv[R * IN_N];
#pragma unroll
        for (int k = 0; k < R * IN_N; ++k) xv[k] = xt[k];   // -> s_load_dwordx16
#pragma unroll
        for (int r = 0; r < R; ++r) STEP(r, xv[2 * r], xv[2 * r + 1])
    }
#pragma unroll 2
    for (int t = T_STEPS - TAIL; t < T_STEPS; ++t) {
        const float* xt = xb + (size_t)t * (BATCH * IN_N);
        float xv[R * IN_N];
#pragma unroll
        for (int k = 0; k < R * IN_N; ++k) xv[k] = xt[k];
#pragma unroll
        for (int r = 0; r < R; ++r) {
            STEP(r, xv[2 * r], xv[2 * r + 1])
            cnt[r] += spk[r];   // integer-valued, exact in fp32
        }
    }
#undef STEP

    // ---- epilogue: out[b0+r, o] = (cnt[r]/10) dot W2[o,:] over h ----
    const float w2a = W2[h];
    const float w2b = W2[HID + h];
    float p0[R], p1[R];
#pragma unroll
    for (int r = 0; r < R; ++r) {
        const float avg = cnt[r] / 10.0f;
        p0[r] = avg * w2a;
        p1[r] = avg * w2b;
    }

    // wave (64-lane) shuffle reduction — same order as the R1-passing kernel
#pragma unroll
    for (int off = 32; off > 0; off >>= 1) {
#pragma unroll
        for (int r = 0; r < R; ++r) {
            p0[r] += __shfl_down(p0[r], off, 64);
            p1[r] += __shfl_down(p1[r], off, 64);
        }
    }

    __shared__ float red[4][R][OUT_N];
    const int wave = h >> 6;
    const int lane = h & 63;
    if (lane == 0) {
#pragma unroll
        for (int r = 0; r < R; ++r) { red[wave][r][0] = p0[r]; red[wave][r][1] = p1[r]; }
    }
    __syncthreads();
    if (h < R * OUT_N) {
        const int r = h >> 1, o = h & 1;
        out[(size_t)(b0 + r) * OUT_N + o] =
            (red[0][r][o] + red[1][r][o]) + (red[2][r][o] + red[3][r][o]);
    }
}

extern "C" void kernel_launch(void* const* d_in, const int* in_sizes, int n_in,
                              void* d_out, int out_size, void* d_ws, size_t ws_size,
                              hipStream_t stream) {
    const float* x  = (const float*)d_in[0];  // (128, 8192, 2)
    const float* W1 = (const float*)d_in[1];  // (256, 2)
    const float* W2 = (const float*)d_in[2];  // (2, 256)
    float* out = (float*)d_out;               // (8192, 2)

    snn_fwd<<<BATCH / R, HID, 0, stream>>>(x, W1, W2, out);
}

// Round 4
// 105.077 us; speedup vs baseline: 1.0833x; 1.0833x over previous
//
#include <hip/hip_runtime.h>

// SNN forward: T=128, B=8192, I=2, H=256, O=2
//  cur[t,b,h] = x[t,b,0]*W1[h,0] + x[t,b,1]*W1[h,1]
//  scan: reset = (mem>1); mem = 0.9*mem + cur - reset; spk = (mem>1)
//  out[b,o] = (mean of spk over last 10 t) dot W2[o,:]
//
// R4: transposed parallelization. Lane = batch row (64 consecutive b per wave),
// thread = RH=8 hidden chains in registers. The per-t x read becomes ONE
// coalesced global_load_dwordx2 per thread (512 B/wave, vmcnt-tracked ->
// deeply pipelined, L1/L2-served). No LDS in the hot loop (R2 was bound on
// broadcast ds_read_b128 through the CU-shared LDS pipe), no scalar loads
// (R3's s_loads serialized on unordered-lgkmcnt drains).
// Block = 256 thr = 4 waves = 32 h for 64 b. 8 h-group blocks cover H=256;
// their partial dot-products land in d_ws and a tiny second kernel sums them.
//
// Spike-path numerics: per-op fp32 rounding (__fmul_rn/__fadd_rn/__fsub_rn),
// identical op order to the R1/R2 kernels that measured absmax 0.0. The
// output-GEMM summation order differs (h-chunked) — rounding diffs ~1e-6,
// far below the 1.7e-3 threshold.

#define T_STEPS 128
#define BATCH   8192
#define HID     256
#define TAIL    10
#define RH      8      // hidden chains per thread
#define LB      64     // batch rows per block (= lanes per wave)
#define NWAVE   4      // waves per block; block covers NWAVE*RH = 32 h
#define HG      8      // h-groups (HID / 32)

__global__ __launch_bounds__(256) void snn_scan(const float* __restrict__ x,
                                                const float* __restrict__ W1,
                                                const float* __restrict__ W2,
                                                float2* __restrict__ partial) {
    const int tid   = threadIdx.x;
    const int lane  = tid & 63;
    const int wave  = tid >> 6;
    const int hg    = blockIdx.x & (HG - 1);   // consecutive blocks -> different XCDs
    const int bg    = blockIdx.x >> 3;
    const int b     = bg * LB + lane;
    const int hbase = hg * (NWAVE * RH) + wave * RH;

    // W1 rows for my 8 h (wave-uniform addresses -> scalarized, one-time)
    float w0[RH], w1[RH];
#pragma unroll
    for (int r = 0; r < RH; ++r) {
        w0[r] = W1[2 * (hbase + r)];
        w1[r] = W1[2 * (hbase + r) + 1];
    }

    // x[t, b, 0:2] lives at xb[t * BATCH] (float2), per-lane coalesced
    const float2* xb = (const float2*)x + b;

    float mem[RH], spk[RH], cnt[RH];
#pragma unroll
    for (int r = 0; r < RH; ++r) { mem[r] = 0.0f; spk[r] = 0.0f; cnt[r] = 0.0f; }

#define STEP(r, xa, xc)                                                          \
    {                                                                            \
        const float c = __fadd_rn(__fmul_rn((xa), w0[r]), __fmul_rn((xc), w1[r]));\
        mem[r] = __fsub_rn(__fadd_rn(__fmul_rn(0.9f, mem[r]), c), spk[r]);       \
        spk[r] = (mem[r] > 1.0f) ? 1.0f : 0.0f;                                  \
    }

#pragma unroll 4
    for (int t = 0; t < T_STEPS - TAIL; ++t) {
        const float2 xv = xb[(size_t)t * BATCH];
#pragma unroll
        for (int r = 0; r < RH; ++r) STEP(r, xv.x, xv.y)
    }
#pragma unroll
    for (int t = T_STEPS - TAIL; t < T_STEPS; ++t) {
        const float2 xv = xb[(size_t)t * BATCH];
#pragma unroll
        for (int r = 0; r < RH; ++r) {
            STEP(r, xv.x, xv.y)
            cnt[r] += spk[r];   // integer-valued, exact in fp32
        }
    }
#undef STEP

    // per-thread partial of out[b, :] over my 8 h
    float p0 = 0.0f, p1 = 0.0f;
#pragma unroll
    for (int r = 0; r < RH; ++r) {
        const float avg = cnt[r] / 10.0f;
        p0 = __fadd_rn(p0, __fmul_rn(avg, W2[hbase + r]));
        p1 = __fadd_rn(p1, __fmul_rn(avg, W2[HID + hbase + r]));
    }

    // combine the block's 4 waves (different h-chunks, same b per lane)
    __shared__ float2 red[NWAVE][LB];
    red[wave][lane] = make_float2(p0, p1);
    __syncthreads();
    if (wave == 0) {
        const float2 a0 = red[0][lane], a1 = red[1][lane];
        const float2 a2 = red[2][lane], a3 = red[3][lane];
        float2 s;
        s.x = __fadd_rn(__fadd_rn(a0.x, a1.x), __fadd_rn(a2.x, a3.x));
        s.y = __fadd_rn(__fadd_rn(a0.y, a1.y), __fadd_rn(a2.y, a3.y));
        partial[(size_t)hg * BATCH + b] = s;
    }
}

// sum the 8 h-group partials -> out[b, 0:2]
__global__ __launch_bounds__(256) void snn_reduce(const float2* __restrict__ partial,
                                                  float2* __restrict__ out) {
    const int b = blockIdx.x * 256 + threadIdx.x;   // 8192 threads
    float sx = 0.0f, sy = 0.0f;
#pragma unroll
    for (int hg = 0; hg < HG; ++hg) {
        const float2 p = partial[(size_t)hg * BATCH + b];
        sx = __fadd_rn(sx, p.x);
        sy = __fadd_rn(sy, p.y);
    }
    out[b] = make_float2(sx, sy);
}

extern "C" void kernel_launch(void* const* d_in, const int* in_sizes, int n_in,
                              void* d_out, int out_size, void* d_ws, size_t ws_size,
                              hipStream_t stream) {
    const float* x  = (const float*)d_in[0];  // (128, 8192, 2)
    const float* W1 = (const float*)d_in[1];  // (256, 2)
    const float* W2 = (const float*)d_in[2];  // (2, 256)
    float2* out     = (float2*)d_out;         // (8192, 2)
    float2* partial = (float2*)d_ws;          // (8, 8192) float2 = 512 KB

    snn_scan<<<(BATCH / LB) * HG, 256, 0, stream>>>(x, W1, W2, partial);
    snn_reduce<<<BATCH / 256, 256, 0, stream>>>(partial, out);
}

// Round 5
// 103.080 us; speedup vs baseline: 1.1043x; 1.0194x over previous
//
#include <hip/hip_runtime.h>

// SNN forward: T=128, B=8192, I=2, H=256, O=2
//  cur[t,b,h] = x[t,b,0]*W1[h,0] + x[t,b,1]*W1[h,1]
//  scan: reset = (mem>1); mem = 0.9*mem + cur - reset; spk = (mem>1)
//  out[b,o] = (mean of spk over last 10 t) dot W2[o,:]
//
// R5 = R4 (lane=batch, RH=8 hidden chains/thread, coalesced float2 x loads)
// plus two latency fixes:
//  (1) XCD-correct swizzle: bg = blockIdx&127, hg = blockIdx>>7. All 8
//      hg-blocks sharing one x-slice land on XCD bg%8 (round-robin blockIdx%8,
//      128 == 0 mod 8) and run concurrently -> one L2 fill serves 8 blocks.
//      (R4 had hg = blockIdx&7, scattering the sharers across all 8 XCDs ->
//      4x HBM over-fetch and ~900-cyc miss latency in the loop.)
//  (2) Explicit depth-8 rotating register prefetch: 8 float2 loads in flight
//      -> 1024 cyc of compute cover per wave, hides even raw HBM latency;
//      in-order VMEM gives fine-grained vmcnt waits (unlike R3's s_loads).
//
// Spike-path numerics: per-op fp32 rounding (__fmul_rn/__fadd_rn/__fsub_rn),
// identical op order + identical epilogue reduction order to R4 (absmax 0.0).

#define T_STEPS 128
#define BATCH   8192
#define HID     256
#define TAIL    10
#define RH      8      // hidden chains per thread
#define LB      64     // batch rows per block (= lanes per wave)
#define NWAVE   4      // waves per block; block covers NWAVE*RH = 32 h
#define HG      8      // h-groups (HID / 32)
#define NBG     (BATCH / LB)   // 128 batch groups
#define PF      8      // prefetch depth (t-steps in flight)

__global__ __launch_bounds__(256) void snn_scan(const float* __restrict__ x,
                                                const float* __restrict__ W1,
                                                const float* __restrict__ W2,
                                                float2* __restrict__ partial) {
    const int tid   = threadIdx.x;
    const int lane  = tid & 63;
    const int wave  = tid >> 6;
    const int bg    = blockIdx.x & (NBG - 1);  // same bg -> same XCD for all hg
    const int hg    = blockIdx.x >> 7;
    const int b     = bg * LB + lane;
    const int hbase = hg * (NWAVE * RH) + wave * RH;

    // W1 rows for my 8 h (wave-uniform addresses -> scalarized, one-time)
    float w0[RH], w1[RH];
#pragma unroll
    for (int r = 0; r < RH; ++r) {
        w0[r] = W1[2 * (hbase + r)];
        w1[r] = W1[2 * (hbase + r) + 1];
    }

    // x[t, b, 0:2] lives at xb[t * BATCH] (float2), per-lane coalesced
    const float2* xb = (const float2*)x + b;

    float mem[RH], spk[RH], cnt[RH];
#pragma unroll
    for (int r = 0; r < RH; ++r) { mem[r] = 0.0f; spk[r] = 0.0f; cnt[r] = 0.0f; }

#define STEP(r, xa, xc)                                                           \
    {                                                                             \
        const float c = __fadd_rn(__fmul_rn((xa), w0[r]), __fmul_rn((xc), w1[r]));\
        mem[r] = __fsub_rn(__fadd_rn(__fmul_rn(0.9f, mem[r]), c), spk[r]);        \
        spk[r] = (mem[r] > 1.0f) ? 1.0f : 0.0f;                                   \
    }

    // ---- warm-up: fill the rotating prefetch buffer with t = 0..7 ----
    float2 buf[PF];
#pragma unroll
    for (int j = 0; j < PF; ++j) buf[j] = xb[(size_t)j * BATCH];

    // ---- main loop: t = 0..111, steady-state depth-8 prefetch ----
    for (int tb = 0; tb < T_STEPS - 2 * PF; tb += PF) {   // 14 iterations
#pragma unroll
        for (int j = 0; j < PF; ++j) {
            const float2 xv = buf[j];
            buf[j] = xb[(size_t)(tb + PF + j) * BATCH];   // prefetch t+8
#pragma unroll
            for (int r = 0; r < RH; ++r) STEP(r, xv.x, xv.y)
        }
    }

    // buf now holds t = 112..119; issue loads for t = 120..127 first
    float2 buf2[PF];
#pragma unroll
    for (int j = 0; j < PF; ++j) buf2[j] = xb[(size_t)(T_STEPS - PF + j) * BATCH];

    // ---- t = 112..119 (cnt for t >= 118) ----
#pragma unroll
    for (int j = 0; j < PF; ++j) {
        const float2 xv = buf[j];
#pragma unroll
        for (int r = 0; r < RH; ++r) {
            STEP(r, xv.x, xv.y)
            if (j >= PF - 2) cnt[r] += spk[r];   // t = 118, 119
        }
    }
    // ---- t = 120..127 (all counted) ----
#pragma unroll
    for (int j = 0; j < PF; ++j) {
        const float2 xv = buf2[j];
#pragma unroll
        for (int r = 0; r < RH; ++r) {
            STEP(r, xv.x, xv.y)
            cnt[r] += spk[r];   // integer-valued, exact in fp32
        }
    }
#undef STEP

    // per-thread partial of out[b, :] over my 8 h
    float p0 = 0.0f, p1 = 0.0f;
#pragma unroll
    for (int r = 0; r < RH; ++r) {
        const float avg = cnt[r] / 10.0f;
        p0 = __fadd_rn(p0, __fmul_rn(avg, W2[hbase + r]));
        p1 = __fadd_rn(p1, __fmul_rn(avg, W2[HID + hbase + r]));
    }

    // combine the block's 4 waves (different h-chunks, same b per lane)
    __shared__ float2 red[NWAVE][LB];
    red[wave][lane] = make_float2(p0, p1);
    __syncthreads();
    if (wave == 0) {
        const float2 a0 = red[0][lane], a1 = red[1][lane];
        const float2 a2 = red[2][lane], a3 = red[3][lane];
        float2 s;
        s.x = __fadd_rn(__fadd_rn(a0.x, a1.x), __fadd_rn(a2.x, a3.x));
        s.y = __fadd_rn(__fadd_rn(a0.y, a1.y), __fadd_rn(a2.y, a3.y));
        partial[(size_t)hg * BATCH + b] = s;
    }
}

// sum the 8 h-group partials -> out[b, 0:2]
__global__ __launch_bounds__(256) void snn_reduce(const float2* __restrict__ partial,
                                                  float2* __restrict__ out) {
    const int b = blockIdx.x * 256 + threadIdx.x;   // 8192 threads
    float sx = 0.0f, sy = 0.0f;
#pragma unroll
    for (int hg = 0; hg < HG; ++hg) {
        const float2 p = partial[(size_t)hg * BATCH + b];
        sx = __fadd_rn(sx, p.x);
        sy = __fadd_rn(sy, p.y);
    }
    out[b] = make_float2(sx, sy);
}

extern "C" void kernel_launch(void* const* d_in, const int* in_sizes, int n_in,
                              void* d_out, int out_size, void* d_ws, size_t ws_size,
                              hipStream_t stream) {
    const float* x  = (const float*)d_in[0];  // (128, 8192, 2)
    const float* W1 = (const float*)d_in[1];  // (256, 2)
    const float* W2 = (const float*)d_in[2];  // (2, 256)
    float2* out     = (float2*)d_out;         // (8192, 2)
    float2* partial = (float2*)d_ws;          // (8, 8192) float2 = 512 KB

    snn_scan<<<NBG * HG, 256, 0, stream>>>(x, W1, W2, partial);
    snn_reduce<<<BATCH / 256, 256, 0, stream>>>(partial, out);
}